// Round 11
// baseline (205.677 us; speedup 1.0000x reference)
//
#include <hip/hip_runtime.h>
#include <hip/hip_bf16.h>

// Round 26: gemm2 rebuilt as 512-thread 128x128 3-ring. Budget analysis: all
// non-gemm1 kernels are <42.6us yet sum to ~117us; gemm2_3r (256 threads =
// 1 wave/SIMD, 240 blocks = 1 blk/CU) runs its pipeline latency-naked -- no
// second wave per SIMD to co-issue against ds_read/vmcnt stalls (m114 overlap
// absent). New gemm2: 512 threads (2 waves/SIMD), 128x128, BK=32, the SAME
// proven 3-ring counted-vmcnt ledger (constants 2/0 instead of 4/0; staging =
// 2 gload16/thread/tile). gemm1 kept at r25 (4-phase measured == r22's 42.6;
// per-tile cost invariant to intra-block scheduling -- at its structural
// ceiling for this family). attn/pack/cvt unchanged.
//
// ws layout (r10):
//   [A] qkv_b16: 3072*3840 bf16   [B] hs_b: 3072*1280 bf16 (-> attn_b)
//   [C] qkvw_b : 3840*1280 bf16 (-> Qp)   [D] projw_b: 1280*1280 bf16
//   [E] Kp 9.4MB   [F] Vp 9.4MB (96-wide, col80 = ones)

#define S_TOT 3072
#define DIM   1280
#define NH    16
#define HD    80
#define SEG   1024
#define TDIM  3840
#define K1    1280

typedef short v8s __attribute__((ext_vector_type(8)));
typedef float v4f __attribute__((ext_vector_type(4)));

__device__ __forceinline__ short f2bf(float v) {
  __hip_bfloat16 b = __float2bfloat16(v);
  return *reinterpret_cast<short*>(&b);
}

__device__ __forceinline__ float bf2f(short s) {
  unsigned u = ((unsigned)(unsigned short)s) << 16;
  float f;
  __builtin_memcpy(&f, &u, 4);
  return f;
}

// async global->LDS, 16B per lane, wave-uniform LDS base + lane*16 dest
__device__ __forceinline__ void gload16(const void* g, void* lds) {
  __builtin_amdgcn_global_load_lds(
      (const __attribute__((address_space(1))) char*)g,
      (__attribute__((address_space(3))) char*)lds, 16, 0, 0);
}

#define CVT_N1 (S_TOT * DIM / 4)
#define CVT_N2 (TDIM * DIM / 4)
#define CVT_N3 (DIM * DIM / 4)
__global__ __launch_bounds__(256) void cvt3(const float* __restrict__ in1,
                                            const float* __restrict__ in2,
                                            const float* __restrict__ in3,
                                            __hip_bfloat16* __restrict__ o1,
                                            __hip_bfloat16* __restrict__ o2,
                                            __hip_bfloat16* __restrict__ o3) {
  int i = blockIdx.x * 256 + threadIdx.x;
  const float* in;
  __hip_bfloat16* out;
  if (i < CVT_N1) { in = in1; out = o1; }
  else if (i < CVT_N1 + CVT_N2) { in = in2; out = o2; i -= CVT_N1; }
  else { in = in3; out = o3; i -= CVT_N1 + CVT_N2; }
  const float4 v = ((const float4*)in)[i];
  __hip_bfloat162 p0, p1;
  p0.x = __float2bfloat16(v.x); p0.y = __float2bfloat16(v.y);
  p1.x = __float2bfloat16(v.z); p1.y = __float2bfloat16(v.w);
  __hip_bfloat162* o = (__hip_bfloat162*)(out + (size_t)i * 4);
  o[0] = p0; o[1] = p1;
}

// ====== gemm1_3r: 256x256, BK=32, 3-ring (96KB), 4-phase (r25, proven) ======
extern __shared__ short ring[];

__global__ __launch_bounds__(512, 2) void gemm1_3r(const __hip_bfloat16* __restrict__ A,
                                                   const __hip_bfloat16* __restrict__ B,
                                                   const float* __restrict__ bias,
                                                   __hip_bfloat16* __restrict__ C) {
  const int tid  = threadIdx.x;
  const int wave = tid >> 6;
  const int lane = tid & 63;
  const int quad = lane >> 4;
  const int l16  = lane & 15;
  const int wmp  = wave >> 2;        // 0..1 : wave M-half (128 rows)
  const int wnp  = wave & 3;         // 0..3 : wave N-strip (64 cols)
  const int bm = blockIdx.x * 256;
  const int bn = blockIdx.y * 256;

  const int r0 = ((tid >> 3) << 1) + ((tid >> 2) & 1);   // row 0..127 in half
  const int gs = (tid & 3) ^ ((tid >> 3) & 3);           // source k-chunk
  const short* A0 = (const short*)A + (size_t)(bm + r0) * K1 + gs * 8;
  const short* A1 = A0 + (size_t)128 * K1;
  const short* B0 = (const short*)B + (size_t)(bn + r0) * K1 + gs * 8;
  const short* B1 = B0 + (size_t)128 * K1;
  const int wst = wave * 512;        // wave-uniform LDS offset (shorts)

#define STG(sbuf, ko) do {                              \
    short* d_ = ring + (sbuf) * 16384;                  \
    gload16(A0 + (ko), d_ + wst);                       \
    gload16(A1 + (ko), d_ + 4096 + wst);                \
    gload16(B0 + (ko), d_ + 8192 + wst);                \
    gload16(B1 + (ko), d_ + 12288 + wst);               \
  } while (0)

  const int posA  = quad ^ ((l16 >> 1) & 3);
  const int rbase = (l16 >> 1) * 64 + (l16 & 1) * 32 + posA * 8;
  const int Abase = wmp * 4096 + rbase;          // + i*512 per 16-row step
  const int Bbase = 8192 + wnp * 2048 + rbase;   // + j*512

  v4f acc[8][4];
  const v4f vz = {0.f, 0.f, 0.f, 0.f};
  #pragma unroll
  for (int i = 0; i < 8; ++i)
    #pragma unroll
    for (int j = 0; j < 4; ++j) acc[i][j] = vz;

  STG(0, 0);
  STG(1, 32);
  asm volatile("s_waitcnt vmcnt(4)" ::: "memory");
  __builtin_amdgcn_s_barrier();
  __builtin_amdgcn_sched_barrier(0);

  int cb = 0, sb = 2;                // read buf, stage buf
  for (int t = 0; t < 40; ++t) {
    if (t + 2 < 40) STG(sb, (t + 2) * 32);

    const short* lb = ring + cb * 16384;
    v8s af[8], bf[4];
    #pragma unroll
    for (int i = 0; i < 8; ++i) af[i] = *(const v8s*)&lb[Abase + i * 512];
    #pragma unroll
    for (int j = 0; j < 4; ++j) bf[j] = *(const v8s*)&lb[Bbase + j * 512];

    __builtin_amdgcn_s_setprio(1);
    #pragma unroll
    for (int i = 0; i < 8; ++i)
      #pragma unroll
      for (int j = 0; j < 4; ++j)
        acc[i][j] = __builtin_amdgcn_mfma_f32_16x16x32_bf16(af[i], bf[j], acc[i][j], 0, 0, 0);
    __builtin_amdgcn_s_setprio(0);

    if (t < 39) {
      if (t + 2 < 40) asm volatile("s_waitcnt vmcnt(4)" ::: "memory");
      else            asm volatile("s_waitcnt vmcnt(0)" ::: "memory");
      __builtin_amdgcn_s_barrier();
      __builtin_amdgcn_sched_barrier(0);
    }
    cb = (cb == 2) ? 0 : cb + 1;
    sb = (sb == 2) ? 0 : sb + 1;
  }
#undef STG

  #pragma unroll
  for (int j = 0; j < 4; ++j) {
    const int col = bn + wnp * 64 + j * 16 + l16;
    const float bj = bias[col];
    #pragma unroll
    for (int i = 0; i < 8; ++i) {
      const int row0 = bm + wmp * 128 + i * 16 + quad * 4;
      #pragma unroll
      for (int r = 0; r < 4; ++r)
        C[(size_t)(row0 + r) * TDIM + col] = __float2bfloat16(acc[i][j][r] + bj);
    }
  }
}

// ===== gemm2_3r: 128x128, BK=32, 3-ring (48KB), 512 threads, f32 out ========
// 8 waves (2M x 4N), wave = 64x32, acc[4][2]. Staging = 2 gload16/thread/tile
// (A 512 chunks + B 512 chunks, 1 each). Ledger: counted vmcnt(2), tail 0.
__global__ __launch_bounds__(512, 2) void gemm2_3r(const __hip_bfloat16* __restrict__ A,
                                                   const __hip_bfloat16* __restrict__ B,
                                                   const float* __restrict__ bias,
                                                   float* __restrict__ C) {
  const int tid  = threadIdx.x;
  const int wave = tid >> 6;
  const int lane = tid & 63;
  const int quad = lane >> 4;
  const int l16  = lane & 15;
  const int wmp  = wave >> 2;        // 0..1 : wave M-half (64 rows)
  const int wnp  = wave & 3;         // 0..3 : wave N-strip (32 cols)
  const int bm = blockIdx.x * 128;
  const int bn = blockIdx.y * 128;

  // staging: thread covers chunk tid of A (rows 0..127) and of B
  const int r0 = ((tid >> 3) << 1) + ((tid >> 2) & 1);   // row 0..127
  const int gs = (tid & 3) ^ ((tid >> 3) & 3);           // source k-chunk
  const short* A0 = (const short*)A + (size_t)(bm + r0) * K1 + gs * 8;
  const short* B0 = (const short*)B + (size_t)(bn + r0) * K1 + gs * 8;
  const int wst = wave * 512;        // wave-uniform LDS offset (shorts)

#define STG2(sbuf, ko) do {                             \
    short* d_ = ring + (sbuf) * 8192;                   \
    gload16(A0 + (ko), d_ + wst);                       \
    gload16(B0 + (ko), d_ + 4096 + wst);                \
  } while (0)

  const int posA  = quad ^ ((l16 >> 1) & 3);
  const int rbase = (l16 >> 1) * 64 + (l16 & 1) * 32 + posA * 8;
  const int Abase = wmp * 2048 + rbase;          // + i*512 per 16-row step
  const int Bbase = 4096 + wnp * 1024 + rbase;   // + j*512

  v4f acc[4][2];
  const v4f vz = {0.f, 0.f, 0.f, 0.f};
  #pragma unroll
  for (int i = 0; i < 4; ++i)
    #pragma unroll
    for (int j = 0; j < 2; ++j) acc[i][j] = vz;

  STG2(0, 0);
  STG2(1, 32);
  asm volatile("s_waitcnt vmcnt(2)" ::: "memory");
  __builtin_amdgcn_s_barrier();
  __builtin_amdgcn_sched_barrier(0);

  int cb = 0, sb = 2;
  for (int t = 0; t < 40; ++t) {
    if (t + 2 < 40) STG2(sb, (t + 2) * 32);

    const short* lb = ring + cb * 8192;
    v8s af[4], bf[2];
    #pragma unroll
    for (int i = 0; i < 4; ++i) af[i] = *(const v8s*)&lb[Abase + i * 512];
    #pragma unroll
    for (int j = 0; j < 2; ++j) bf[j] = *(const v8s*)&lb[Bbase + j * 512];

    __builtin_amdgcn_s_setprio(1);
    #pragma unroll
    for (int i = 0; i < 4; ++i)
      #pragma unroll
      for (int j = 0; j < 2; ++j)
        acc[i][j] = __builtin_amdgcn_mfma_f32_16x16x32_bf16(af[i], bf[j], acc[i][j], 0, 0, 0);
    __builtin_amdgcn_s_setprio(0);

    if (t < 39) {
      if (t + 2 < 40) asm volatile("s_waitcnt vmcnt(2)" ::: "memory");
      else            asm volatile("s_waitcnt vmcnt(0)" ::: "memory");
      __builtin_amdgcn_s_barrier();
      __builtin_amdgcn_sched_barrier(0);
    }
    cb = (cb == 2) ? 0 : cb + 1;
    sb = (sb == 2) ? 0 : sb + 1;
  }
#undef STG2

  #pragma unroll
  for (int j = 0; j < 2; ++j) {
    const int col = bn + wnp * 32 + j * 16 + l16;
    const float bj = bias[col];
    #pragma unroll
    for (int i = 0; i < 4; ++i) {
      const int row0 = bm + wmp * 64 + i * 16 + quad * 4;
      #pragma unroll
      for (int r = 0; r < 4; ++r)
        C[(size_t)(row0 + r) * DIM + col] = acc[i][j][r] + bj;
    }
  }
}

// ---------------- merged pack kernel (unchanged) ----------------
#define QK_BLOCKS ((2 * S_TOT * 16 * 12) / 256)   // 4608
#define V_BLOCKS  ((3 * 16 * 16 * 8 * 96) / 256)  // 2304
__global__ __launch_bounds__(256) void pack_all(const __hip_bfloat16* __restrict__ qkv,
                                                const float* __restrict__ cos_,
                                                const float* __restrict__ sin_,
                                                short* __restrict__ Qp,
                                                short* __restrict__ Kp,
                                                short* __restrict__ Vp) {
  const int bid = blockIdx.x;
  if (bid < QK_BLOCKS) {
    const int idx = bid * 256 + threadIdx.x;
    const int kd = idx % 12;
    const int h  = (idx / 12) % 16;
    const int s  = (idx / 192) % S_TOT;
    const int p  = idx / (192 * S_TOT);
    const int seg = s >> 10, tb = (s >> 6) & 15, t = s & 63;
    short* out = (p ? Kp : Qp) +
                 ((size_t)(((seg * 16 + h) * 16 + tb) * 12 + kd) * 64 + t) * 8;
    short tmp[8];
    if (kd >= 10) {
      #pragma unroll
      for (int j = 0; j < 8; ++j) tmp[j] = 0;
      *(int4*)out = *(int4*)tmp;
      return;
    }
    const short* row = (const short*)qkv + (size_t)s * TDIM + p * DIM + h * HD;
    const int d0 = kd * 8;
    const v8s xm = *(const v8s*)(row + d0);
    const v8s xr = *(const v8s*)(row + d0 + ((kd < 5) ? 40 : -40));
    const float sgn = (kd < 5) ? -1.f : 1.f;
    const float scale = (p == 0) ? 0.111803398874989485f : 1.0f;
    #pragma unroll
    for (int j = 0; j < 8; ++j) {
      const int d = d0 + j;
      const float v = (bf2f(xm[j]) * cos_[s * HD + d] +
                       sgn * bf2f(xr[j]) * sin_[s * HD + d]) * scale;
      tmp[j] = f2bf(v);
    }
    *(int4*)out = *(int4*)tmp;
  } else {
    const int idx = (bid - QK_BLOCKS) * 256 + threadIdx.x;
    const int d  = idx % 96;
    const int td = (idx / 96) % 8;
    const int tb = (idx / 768) % 16;
    const int h  = (idx / (768 * 16)) % 16;
    const int seg = idx / (768 * 256);
    const int s0 = seg * SEG + tb * 64 + td * 8;
    const short* q = (const short*)qkv;
    short tmp[8];
    if (d < 80) {
      #pragma unroll
      for (int j = 0; j < 8; ++j)
        tmp[j] = q[(size_t)(s0 + j) * TDIM + 2 * DIM + h * HD + d];
    } else {
      const short fill = (d == 80) ? (short)0x3F80 : (short)0;
      #pragma unroll
      for (int j = 0; j < 8; ++j) tmp[j] = fill;
    }
    *(int4*)(Vp + (size_t)idx * 8) = *(int4*)tmp;
  }
}

// -------- fused flash MFMA attention (r19 XCD group mapping, kept) ----------
__global__ __launch_bounds__(256, 4) void attn_mfma(const short* __restrict__ Qp,
                                                    const short* __restrict__ Kp,
                                                    const short* __restrict__ Vp,
                                                    __hip_bfloat16* __restrict__ out) {
  __shared__ __align__(16) short Ks[64 * 96];
  __shared__ __align__(16) short Vs[64 * 96];
  __shared__ __align__(16) short Ps[4][16 * 68];

  const int l   = blockIdx.x;
  const int xcd = l & 7;
  const int j8  = l >> 3;            // 0..95
  const int g   = xcd * 6 + (j8 >> 4);  // group 0..47  (= seg*16 + h)
  const int qt  = j8 & 15;
  const int h   = g & 15;
  const int seg = g >> 4;
  const int tid  = threadIdx.x;
  const int wave = tid >> 6;
  const int lane = tid & 63;
  const int quad = lane >> 4;
  const int l16  = lane & 15;
  const int sh16 = g;

  const short* Qg = Qp + (size_t)(sh16 * 16 + qt) * 6144;
  const short* Kg = Kp + (size_t)sh16 * 16 * 6144;
  const short* Vg = Vp + (size_t)sh16 * 16 * 6144;

  v8s af[3];
  #pragma unroll
  for (int ks = 0; ks < 3; ++ks)
    af[ks] = *(const v8s*)(Qg + ((ks * 4 + quad) * 64 + wave * 16 + l16) * 8);

  v8s kr[3], vr[3];
  #pragma unroll
  for (int it = 0; it < 3; ++it) {
    const int o = (it * 256 + tid) * 8;
    kr[it] = *(const v8s*)(Kg + o);
    vr[it] = *(const v8s*)(Vg + o);
  }
  #pragma unroll
  for (int it = 0; it < 3; ++it) {
    const int o = (it * 256 + tid) * 8;
    *(v8s*)&Ks[o] = kr[it];
    *(v8s*)&Vs[o] = vr[it];
  }
  __syncthreads();

  v4f o4[6];
  const v4f vz = {0.f, 0.f, 0.f, 0.f};
  #pragma unroll
  for (int n = 0; n < 6; ++n) o4[n] = vz;

  for (int kb = 0; kb < 16; ++kb) {
    const bool more = (kb + 1 < 16);
    if (more) {
      const size_t base = (size_t)(kb + 1) * 6144;
      #pragma unroll
      for (int it = 0; it < 3; ++it) {
        const int o = (it * 256 + tid) * 8;
        kr[it] = *(const v8s*)(Kg + base + o);
        vr[it] = *(const v8s*)(Vg + base + o);
      }
    }

    v4f s4[4];
    #pragma unroll
    for (int j = 0; j < 4; ++j) {
      s4[j] = vz;
      #pragma unroll
      for (int ks = 0; ks < 3; ++ks) {
        const v8s bf = *(const v8s*)&Ks[((ks * 4 + quad) * 64 + j * 16 + l16) * 8];
        s4[j] = __builtin_amdgcn_mfma_f32_16x16x32_bf16(af[ks], bf, s4[j], 0, 0, 0);
      }
    }

    #pragma unroll
    for (int reg = 0; reg < 4; ++reg)
      #pragma unroll
      for (int j = 0; j < 4; ++j)
        Ps[wave][(quad * 4 + reg) * 68 + j * 16 + l16] = f2bf(__expf(s4[j][reg]));

    v8s pa[2];
    #pragma unroll
    for (int kp = 0; kp < 2; ++kp)
      pa[kp] = *(const v8s*)&Ps[wave][l16 * 68 + kp * 32 + quad * 8];
    #pragma unroll
    for (int n = 0; n < 6; ++n) {
      #pragma unroll
      for (int kp = 0; kp < 2; ++kp) {
        const v8s vb = *(const v8s*)&Vs[((kp * 4 + quad) * 96 + n * 16 + l16) * 8];
        o4[n] = __builtin_amdgcn_mfma_f32_16x16x32_bf16(pa[kp], vb, o4[n], 0, 0, 0);
      }
    }

    __syncthreads();
    if (more) {
      #pragma unroll
      for (int it = 0; it < 3; ++it) {
        const int o = (it * 256 + tid) * 8;
        *(v8s*)&Ks[o] = kr[it];
        *(v8s*)&Vs[o] = vr[it];
      }
    }
    __syncthreads();
  }

  float inv[4];
  #pragma unroll
  for (int r = 0; r < 4; ++r)
    inv[r] = 1.f / __shfl(o4[5][r], quad << 4);
  const int row0 = seg * SEG + qt * 64 + wave * 16 + quad * 4;
  #pragma unroll
  for (int n = 0; n < 5; ++n) {
    const int col = h * HD + n * 16 + l16;
    #pragma unroll
    for (int r = 0; r < 4; ++r)
      out[(size_t)(row0 + r) * DIM + col] = __float2bfloat16(o4[n][r] * inv[r]);
  }
}

extern "C" void kernel_launch(void* const* d_in, const int* in_sizes, int n_in,
                              void* d_out, int out_size, void* d_ws, size_t ws_size,
                              hipStream_t stream) {
  (void)in_sizes; (void)n_in; (void)out_size; (void)ws_size;
  const float* hs     = (const float*)d_in[0];
  const float* cosp   = (const float*)d_in[1];
  const float* sinp   = (const float*)d_in[2];
  const float* qkv_w  = (const float*)d_in[3];
  const float* qkv_b  = (const float*)d_in[4];
  const float* proj_w = (const float*)d_in[5];
  const float* proj_b = (const float*)d_in[6];

  float* out_f = (float*)d_out;
  __hip_bfloat16* qkv_b16 = (__hip_bfloat16*)d_ws;                     // [A]
  __hip_bfloat16* hs_b    = qkv_b16 + (size_t)S_TOT * TDIM;            // [B]
  __hip_bfloat16* qkvw_b  = hs_b + (size_t)S_TOT * DIM;                // [C]
  __hip_bfloat16* projw_b = qkvw_b + (size_t)TDIM * DIM;               // [D]
  short* Qp = (short*)qkvw_b;                                          // alias [C]
  short* Kp = (short*)(projw_b + (size_t)DIM * DIM);                   // [E]
  short* Vp = Kp + (size_t)3 * 16 * 16 * 6144;                         // [F]
  __hip_bfloat16* attn_b = hs_b;                                       // alias [B]

  static bool attr_set = false;
  if (!attr_set) {
    hipFuncSetAttribute((const void*)gemm1_3r,
                        hipFuncAttributeMaxDynamicSharedMemorySize, 98304);
    hipFuncSetAttribute((const void*)gemm2_3r,
                        hipFuncAttributeMaxDynamicSharedMemorySize, 49152);
    attr_set = true;
  }

  cvt3<<<(CVT_N1 + CVT_N2 + CVT_N3) / 256, 256, 0, stream>>>(
      hs, qkv_w, proj_w, hs_b, qkvw_b, projw_b);

  gemm1_3r<<<dim3(S_TOT / 256, TDIM / 256), 512, 98304, stream>>>(
      hs_b, qkvw_b, qkv_b, qkv_b16);

  pack_all<<<QK_BLOCKS + V_BLOCKS, 256, 0, stream>>>(qkv_b16, cosp, sinp, Qp, Kp, Vp);

  attn_mfma<<<dim3(768), 256, 0, stream>>>(Qp, Kp, Vp, attn_b);

  gemm2_3r<<<dim3(S_TOT / 128, DIM / 128), 512, 49152, stream>>>(
      attn_b, projw_b, proj_b, out_f);
}

// Round 12
// 200.408 us; speedup vs baseline: 1.0263x; 1.0263x over previous
//
#include <hip/hip_runtime.h>
#include <hip/hip_bf16.h>

// Round 27: gemm2 -> BK=64 (20 K-tiles). Model from r22/r25/r26: at 1 blk/CU
// the 3-ring structure costs ~2500cy/K-tile FIXED (sync+convoy), invariant to
// intra-tile scheduling. gemm2_3r (40 tiles) is therefore ~42us for 7.9 GF --
// invisible in top-5 (gemm1s are 45-46) but the 2nd-largest kernel. Halving
// tile count via BK=64 should halve it. Same proven 3-ring counted-vmcnt
// ledger (stage t+2 -> buf (t+2)%3, 4 loads/stage, vmcnt(4)/0); r15's proven
// 8-chunk swizzle (pos^(row&7), src-side, linear DMA dest). 96KB LDS, 512thr.
// gemm1 = r22 3-ring verbatim. attn XCD map / pack / cvt unchanged.
//
// ws layout (r10):
//   [A] qkv_b16: 3072*3840 bf16   [B] hs_b: 3072*1280 bf16 (-> attn_b)
//   [C] qkvw_b : 3840*1280 bf16 (-> Qp)   [D] projw_b: 1280*1280 bf16
//   [E] Kp 9.4MB   [F] Vp 9.4MB (96-wide, col80 = ones)

#define S_TOT 3072
#define DIM   1280
#define NH    16
#define HD    80
#define SEG   1024
#define TDIM  3840
#define K1    1280

typedef short v8s __attribute__((ext_vector_type(8)));
typedef float v4f __attribute__((ext_vector_type(4)));

__device__ __forceinline__ short f2bf(float v) {
  __hip_bfloat16 b = __float2bfloat16(v);
  return *reinterpret_cast<short*>(&b);
}

__device__ __forceinline__ float bf2f(short s) {
  unsigned u = ((unsigned)(unsigned short)s) << 16;
  float f;
  __builtin_memcpy(&f, &u, 4);
  return f;
}

// async global->LDS, 16B per lane, wave-uniform LDS base + lane*16 dest
__device__ __forceinline__ void gload16(const void* g, void* lds) {
  __builtin_amdgcn_global_load_lds(
      (const __attribute__((address_space(1))) char*)g,
      (__attribute__((address_space(3))) char*)lds, 16, 0, 0);
}

#define CVT_N1 (S_TOT * DIM / 4)
#define CVT_N2 (TDIM * DIM / 4)
#define CVT_N3 (DIM * DIM / 4)
__global__ __launch_bounds__(256) void cvt3(const float* __restrict__ in1,
                                            const float* __restrict__ in2,
                                            const float* __restrict__ in3,
                                            __hip_bfloat16* __restrict__ o1,
                                            __hip_bfloat16* __restrict__ o2,
                                            __hip_bfloat16* __restrict__ o3) {
  int i = blockIdx.x * 256 + threadIdx.x;
  const float* in;
  __hip_bfloat16* out;
  if (i < CVT_N1) { in = in1; out = o1; }
  else if (i < CVT_N1 + CVT_N2) { in = in2; out = o2; i -= CVT_N1; }
  else { in = in3; out = o3; i -= CVT_N1 + CVT_N2; }
  const float4 v = ((const float4*)in)[i];
  __hip_bfloat162 p0, p1;
  p0.x = __float2bfloat16(v.x); p0.y = __float2bfloat16(v.y);
  p1.x = __float2bfloat16(v.z); p1.y = __float2bfloat16(v.w);
  __hip_bfloat162* o = (__hip_bfloat162*)(out + (size_t)i * 4);
  o[0] = p0; o[1] = p1;
}

// ====== gemm1_3r: 256x256, BK=32, 3-ring (96KB), counted vmcnt (r22) ========
extern __shared__ short ring[];

__global__ __launch_bounds__(512, 2) void gemm1_3r(const __hip_bfloat16* __restrict__ A,
                                                   const __hip_bfloat16* __restrict__ B,
                                                   const float* __restrict__ bias,
                                                   __hip_bfloat16* __restrict__ C) {
  const int tid  = threadIdx.x;
  const int wave = tid >> 6;
  const int lane = tid & 63;
  const int quad = lane >> 4;
  const int l16  = lane & 15;
  const int wmp  = wave >> 2;        // 0..1 : wave M-half (128 rows)
  const int wnp  = wave & 3;         // 0..3 : wave N-strip (64 cols)
  const int bm = blockIdx.x * 256;
  const int bn = blockIdx.y * 256;

  const int r0 = ((tid >> 3) << 1) + ((tid >> 2) & 1);   // row 0..127 in half
  const int gs = (tid & 3) ^ ((tid >> 3) & 3);           // source k-chunk
  const short* A0 = (const short*)A + (size_t)(bm + r0) * K1 + gs * 8;
  const short* A1 = A0 + (size_t)128 * K1;
  const short* B0 = (const short*)B + (size_t)(bn + r0) * K1 + gs * 8;
  const short* B1 = B0 + (size_t)128 * K1;
  const int wst = wave * 512;        // wave-uniform LDS offset (shorts)

#define STG(sbuf, ko) do {                              \
    short* d_ = ring + (sbuf) * 16384;                  \
    gload16(A0 + (ko), d_ + wst);                       \
    gload16(A1 + (ko), d_ + 4096 + wst);                \
    gload16(B0 + (ko), d_ + 8192 + wst);                \
    gload16(B1 + (ko), d_ + 12288 + wst);               \
  } while (0)

  const int posA  = quad ^ ((l16 >> 1) & 3);
  const int rbase = (l16 >> 1) * 64 + (l16 & 1) * 32 + posA * 8;
  const int Abase = wmp * 4096 + rbase;          // + i*512 per 16-row step
  const int Bbase = 8192 + wnp * 2048 + rbase;   // + j*512

  v4f acc[8][4];
  const v4f vz = {0.f, 0.f, 0.f, 0.f};
  #pragma unroll
  for (int i = 0; i < 8; ++i)
    #pragma unroll
    for (int j = 0; j < 4; ++j) acc[i][j] = vz;

  STG(0, 0);
  STG(1, 32);
  asm volatile("s_waitcnt vmcnt(4)" ::: "memory");
  __builtin_amdgcn_s_barrier();
  __builtin_amdgcn_sched_barrier(0);

  int cb = 0, sb = 2;                // read buf, stage buf
  for (int t = 0; t < 40; ++t) {
    if (t + 2 < 40) STG(sb, (t + 2) * 32);

    const short* lb = ring + cb * 16384;
    v8s af[8], bf[4];
    #pragma unroll
    for (int i = 0; i < 8; ++i) af[i] = *(const v8s*)&lb[Abase + i * 512];
    #pragma unroll
    for (int j = 0; j < 4; ++j) bf[j] = *(const v8s*)&lb[Bbase + j * 512];

    __builtin_amdgcn_s_setprio(1);
    #pragma unroll
    for (int i = 0; i < 8; ++i)
      #pragma unroll
      for (int j = 0; j < 4; ++j)
        acc[i][j] = __builtin_amdgcn_mfma_f32_16x16x32_bf16(af[i], bf[j], acc[i][j], 0, 0, 0);
    __builtin_amdgcn_s_setprio(0);

    if (t < 39) {
      if (t + 2 < 40) asm volatile("s_waitcnt vmcnt(4)" ::: "memory");
      else            asm volatile("s_waitcnt vmcnt(0)" ::: "memory");
      __builtin_amdgcn_s_barrier();
      __builtin_amdgcn_sched_barrier(0);
    }
    cb = (cb == 2) ? 0 : cb + 1;
    sb = (sb == 2) ? 0 : sb + 1;
  }
#undef STG

  #pragma unroll
  for (int j = 0; j < 4; ++j) {
    const int col = bn + wnp * 64 + j * 16 + l16;
    const float bj = bias[col];
    #pragma unroll
    for (int i = 0; i < 8; ++i) {
      const int row0 = bm + wmp * 128 + i * 16 + quad * 4;
      #pragma unroll
      for (int r = 0; r < 4; ++r)
        C[(size_t)(row0 + r) * TDIM + col] = __float2bfloat16(acc[i][j][r] + bj);
    }
  }
}

// ===== gemm2_3r: 128x128, BK=64, 3-ring (96KB), 512 threads, f32 out ========
// 20 K-tiles (vs 40): halves the fixed per-tile sync cost. LDS buffer b at
// b*16384 shorts: A (128 rows x 8 chunks) at +0, B at +8192. Chunk (row,pos)
// at row*64 + pos*8 shorts, holds global k-chunk pos ^ (row&7) (r15-proven).
// Ledger identical to gemm1: stage t+2 (4 loads), vmcnt(4)/tail-0.
__global__ __launch_bounds__(512, 2) void gemm2_3r(const __hip_bfloat16* __restrict__ A,
                                                   const __hip_bfloat16* __restrict__ B,
                                                   const float* __restrict__ bias,
                                                   float* __restrict__ C) {
  const int tid  = threadIdx.x;
  const int wave = tid >> 6;
  const int lane = tid & 63;
  const int quad = lane >> 4;
  const int l16  = lane & 15;
  const int wmp  = wave >> 2;        // 0..1 : wave M-half (64 rows)
  const int wnp  = wave & 3;         // 0..3 : wave N-strip (32 cols)
  const int bm = blockIdx.x * 128;
  const int bn = blockIdx.y * 128;

  // staging: thread covers chunk tid (row tid>>3, pos tid&7) of each 64-row half
  const int r0 = tid >> 3;           // 0..63
  const int p0 = tid & 7;
  const int gsw = p0 ^ (r0 & 7);     // pre-swizzled source k-chunk ((r0+64)&7==r0&7)
  const short* A0 = (const short*)A + (size_t)(bm + r0) * K1 + gsw * 8;
  const short* A1 = A0 + (size_t)64 * K1;
  const short* B0 = (const short*)B + (size_t)(bn + r0) * K1 + gsw * 8;
  const short* B1 = B0 + (size_t)64 * K1;
  const int wst = wave * 512;        // wave-uniform LDS offset (shorts)

#define STG2(sbuf, ko) do {                             \
    short* d_ = ring + (sbuf) * 16384;                  \
    gload16(A0 + (ko), d_ + wst);                       \
    gload16(A1 + (ko), d_ + 4096 + wst);                \
    gload16(B0 + (ko), d_ + 8192 + wst);                \
    gload16(B1 + (ko), d_ + 12288 + wst);               \
  } while (0)

  // read-side: frag row = base + i*16 + l16; chunk g = s*4+quad stored at
  // (g ^ (row&7)) = (g ^ (l16&7)) since bases are multiples of 16.
  const int foff0 = l16 * 64 + ((quad) ^ (l16 & 7)) * 8;
  const int foff1 = l16 * 64 + ((4 + quad) ^ (l16 & 7)) * 8;
  const int Ab = wmp * 4096;             // + i*1024 per 16-row step
  const int Bb = 8192 + wnp * 2048;      // + j*1024

  v4f acc[4][2];
  const v4f vz = {0.f, 0.f, 0.f, 0.f};
  #pragma unroll
  for (int i = 0; i < 4; ++i)
    #pragma unroll
    for (int j = 0; j < 2; ++j) acc[i][j] = vz;

  STG2(0, 0);
  STG2(1, 64);
  asm volatile("s_waitcnt vmcnt(4)" ::: "memory");
  __builtin_amdgcn_s_barrier();
  __builtin_amdgcn_sched_barrier(0);

  int cb = 0, sb = 2;
  for (int t = 0; t < 20; ++t) {
    if (t + 2 < 20) STG2(sb, (t + 2) * 64);

    const short* lb = ring + cb * 16384;
    #pragma unroll
    for (int s = 0; s < 2; ++s) {
      const int foff = s ? foff1 : foff0;
      v8s af[4], bf[2];
      #pragma unroll
      for (int i = 0; i < 4; ++i) af[i] = *(const v8s*)&lb[Ab + i * 1024 + foff];
      #pragma unroll
      for (int j = 0; j < 2; ++j) bf[j] = *(const v8s*)&lb[Bb + j * 1024 + foff];
      __builtin_amdgcn_s_setprio(1);
      #pragma unroll
      for (int i = 0; i < 4; ++i)
        #pragma unroll
        for (int j = 0; j < 2; ++j)
          acc[i][j] = __builtin_amdgcn_mfma_f32_16x16x32_bf16(af[i], bf[j], acc[i][j], 0, 0, 0);
      __builtin_amdgcn_s_setprio(0);
    }

    if (t < 19) {
      if (t + 2 < 20) asm volatile("s_waitcnt vmcnt(4)" ::: "memory");
      else            asm volatile("s_waitcnt vmcnt(0)" ::: "memory");
      __builtin_amdgcn_s_barrier();
      __builtin_amdgcn_sched_barrier(0);
    }
    cb = (cb == 2) ? 0 : cb + 1;
    sb = (sb == 2) ? 0 : sb + 1;
  }
#undef STG2

  #pragma unroll
  for (int j = 0; j < 2; ++j) {
    const int col = bn + wnp * 32 + j * 16 + l16;
    const float bj = bias[col];
    #pragma unroll
    for (int i = 0; i < 4; ++i) {
      const int row0 = bm + wmp * 64 + i * 16 + quad * 4;
      #pragma unroll
      for (int r = 0; r < 4; ++r)
        C[(size_t)(row0 + r) * DIM + col] = acc[i][j][r] + bj;
    }
  }
}

// ---------------- merged pack kernel (unchanged) ----------------
#define QK_BLOCKS ((2 * S_TOT * 16 * 12) / 256)   // 4608
#define V_BLOCKS  ((3 * 16 * 16 * 8 * 96) / 256)  // 2304
__global__ __launch_bounds__(256) void pack_all(const __hip_bfloat16* __restrict__ qkv,
                                                const float* __restrict__ cos_,
                                                const float* __restrict__ sin_,
                                                short* __restrict__ Qp,
                                                short* __restrict__ Kp,
                                                short* __restrict__ Vp) {
  const int bid = blockIdx.x;
  if (bid < QK_BLOCKS) {
    const int idx = bid * 256 + threadIdx.x;
    const int kd = idx % 12;
    const int h  = (idx / 12) % 16;
    const int s  = (idx / 192) % S_TOT;
    const int p  = idx / (192 * S_TOT);
    const int seg = s >> 10, tb = (s >> 6) & 15, t = s & 63;
    short* out = (p ? Kp : Qp) +
                 ((size_t)(((seg * 16 + h) * 16 + tb) * 12 + kd) * 64 + t) * 8;
    short tmp[8];
    if (kd >= 10) {
      #pragma unroll
      for (int j = 0; j < 8; ++j) tmp[j] = 0;
      *(int4*)out = *(int4*)tmp;
      return;
    }
    const short* row = (const short*)qkv + (size_t)s * TDIM + p * DIM + h * HD;
    const int d0 = kd * 8;
    const v8s xm = *(const v8s*)(row + d0);
    const v8s xr = *(const v8s*)(row + d0 + ((kd < 5) ? 40 : -40));
    const float sgn = (kd < 5) ? -1.f : 1.f;
    const float scale = (p == 0) ? 0.111803398874989485f : 1.0f;
    #pragma unroll
    for (int j = 0; j < 8; ++j) {
      const int d = d0 + j;
      const float v = (bf2f(xm[j]) * cos_[s * HD + d] +
                       sgn * bf2f(xr[j]) * sin_[s * HD + d]) * scale;
      tmp[j] = f2bf(v);
    }
    *(int4*)out = *(int4*)tmp;
  } else {
    const int idx = (bid - QK_BLOCKS) * 256 + threadIdx.x;
    const int d  = idx % 96;
    const int td = (idx / 96) % 8;
    const int tb = (idx / 768) % 16;
    const int h  = (idx / (768 * 16)) % 16;
    const int seg = idx / (768 * 256);
    const int s0 = seg * SEG + tb * 64 + td * 8;
    const short* q = (const short*)qkv;
    short tmp[8];
    if (d < 80) {
      #pragma unroll
      for (int j = 0; j < 8; ++j)
        tmp[j] = q[(size_t)(s0 + j) * TDIM + 2 * DIM + h * HD + d];
    } else {
      const short fill = (d == 80) ? (short)0x3F80 : (short)0;
      #pragma unroll
      for (int j = 0; j < 8; ++j) tmp[j] = fill;
    }
    *(int4*)(Vp + (size_t)idx * 8) = *(int4*)tmp;
  }
}

// -------- fused flash MFMA attention (r19 XCD group mapping, kept) ----------
__global__ __launch_bounds__(256, 4) void attn_mfma(const short* __restrict__ Qp,
                                                    const short* __restrict__ Kp,
                                                    const short* __restrict__ Vp,
                                                    __hip_bfloat16* __restrict__ out) {
  __shared__ __align__(16) short Ks[64 * 96];
  __shared__ __align__(16) short Vs[64 * 96];
  __shared__ __align__(16) short Ps[4][16 * 68];

  const int l   = blockIdx.x;
  const int xcd = l & 7;
  const int j8  = l >> 3;            // 0..95
  const int g   = xcd * 6 + (j8 >> 4);  // group 0..47  (= seg*16 + h)
  const int qt  = j8 & 15;
  const int h   = g & 15;
  const int seg = g >> 4;
  const int tid  = threadIdx.x;
  const int wave = tid >> 6;
  const int lane = tid & 63;
  const int quad = lane >> 4;
  const int l16  = lane & 15;
  const int sh16 = g;

  const short* Qg = Qp + (size_t)(sh16 * 16 + qt) * 6144;
  const short* Kg = Kp + (size_t)sh16 * 16 * 6144;
  const short* Vg = Vp + (size_t)sh16 * 16 * 6144;

  v8s af[3];
  #pragma unroll
  for (int ks = 0; ks < 3; ++ks)
    af[ks] = *(const v8s*)(Qg + ((ks * 4 + quad) * 64 + wave * 16 + l16) * 8);

  v8s kr[3], vr[3];
  #pragma unroll
  for (int it = 0; it < 3; ++it) {
    const int o = (it * 256 + tid) * 8;
    kr[it] = *(const v8s*)(Kg + o);
    vr[it] = *(const v8s*)(Vg + o);
  }
  #pragma unroll
  for (int it = 0; it < 3; ++it) {
    const int o = (it * 256 + tid) * 8;
    *(v8s*)&Ks[o] = kr[it];
    *(v8s*)&Vs[o] = vr[it];
  }
  __syncthreads();

  v4f o4[6];
  const v4f vz = {0.f, 0.f, 0.f, 0.f};
  #pragma unroll
  for (int n = 0; n < 6; ++n) o4[n] = vz;

  for (int kb = 0; kb < 16; ++kb) {
    const bool more = (kb + 1 < 16);
    if (more) {
      const size_t base = (size_t)(kb + 1) * 6144;
      #pragma unroll
      for (int it = 0; it < 3; ++it) {
        const int o = (it * 256 + tid) * 8;
        kr[it] = *(const v8s*)(Kg + base + o);
        vr[it] = *(const v8s*)(Vg + base + o);
      }
    }

    v4f s4[4];
    #pragma unroll
    for (int j = 0; j < 4; ++j) {
      s4[j] = vz;
      #pragma unroll
      for (int ks = 0; ks < 3; ++ks) {
        const v8s bf = *(const v8s*)&Ks[((ks * 4 + quad) * 64 + j * 16 + l16) * 8];
        s4[j] = __builtin_amdgcn_mfma_f32_16x16x32_bf16(af[ks], bf, s4[j], 0, 0, 0);
      }
    }

    #pragma unroll
    for (int reg = 0; reg < 4; ++reg)
      #pragma unroll
      for (int j = 0; j < 4; ++j)
        Ps[wave][(quad * 4 + reg) * 68 + j * 16 + l16] = f2bf(__expf(s4[j][reg]));

    v8s pa[2];
    #pragma unroll
    for (int kp = 0; kp < 2; ++kp)
      pa[kp] = *(const v8s*)&Ps[wave][l16 * 68 + kp * 32 + quad * 8];
    #pragma unroll
    for (int n = 0; n < 6; ++n) {
      #pragma unroll
      for (int kp = 0; kp < 2; ++kp) {
        const v8s vb = *(const v8s*)&Vs[((kp * 4 + quad) * 96 + n * 16 + l16) * 8];
        o4[n] = __builtin_amdgcn_mfma_f32_16x16x32_bf16(pa[kp], vb, o4[n], 0, 0, 0);
      }
    }

    __syncthreads();
    if (more) {
      #pragma unroll
      for (int it = 0; it < 3; ++it) {
        const int o = (it * 256 + tid) * 8;
        *(v8s*)&Ks[o] = kr[it];
        *(v8s*)&Vs[o] = vr[it];
      }
    }
    __syncthreads();
  }

  float inv[4];
  #pragma unroll
  for (int r = 0; r < 4; ++r)
    inv[r] = 1.f / __shfl(o4[5][r], quad << 4);
  const int row0 = seg * SEG + qt * 64 + wave * 16 + quad * 4;
  #pragma unroll
  for (int n = 0; n < 5; ++n) {
    const int col = h * HD + n * 16 + l16;
    #pragma unroll
    for (int r = 0; r < 4; ++r)
      out[(size_t)(row0 + r) * DIM + col] = __float2bfloat16(o4[n][r] * inv[r]);
  }
}

extern "C" void kernel_launch(void* const* d_in, const int* in_sizes, int n_in,
                              void* d_out, int out_size, void* d_ws, size_t ws_size,
                              hipStream_t stream) {
  (void)in_sizes; (void)n_in; (void)out_size; (void)ws_size;
  const float* hs     = (const float*)d_in[0];
  const float* cosp   = (const float*)d_in[1];
  const float* sinp   = (const float*)d_in[2];
  const float* qkv_w  = (const float*)d_in[3];
  const float* qkv_b  = (const float*)d_in[4];
  const float* proj_w = (const float*)d_in[5];
  const float* proj_b = (const float*)d_in[6];

  float* out_f = (float*)d_out;
  __hip_bfloat16* qkv_b16 = (__hip_bfloat16*)d_ws;                     // [A]
  __hip_bfloat16* hs_b    = qkv_b16 + (size_t)S_TOT * TDIM;            // [B]
  __hip_bfloat16* qkvw_b  = hs_b + (size_t)S_TOT * DIM;                // [C]
  __hip_bfloat16* projw_b = qkvw_b + (size_t)TDIM * DIM;               // [D]
  short* Qp = (short*)qkvw_b;                                          // alias [C]
  short* Kp = (short*)(projw_b + (size_t)DIM * DIM);                   // [E]
  short* Vp = Kp + (size_t)3 * 16 * 16 * 6144;                         // [F]
  __hip_bfloat16* attn_b = hs_b;                                       // alias [B]

  static bool attr_set = false;
  if (!attr_set) {
    hipFuncSetAttribute((const void*)gemm1_3r,
                        hipFuncAttributeMaxDynamicSharedMemorySize, 98304);
    hipFuncSetAttribute((const void*)gemm2_3r,
                        hipFuncAttributeMaxDynamicSharedMemorySize, 98304);
    attr_set = true;
  }

  cvt3<<<(CVT_N1 + CVT_N2 + CVT_N3) / 256, 256, 0, stream>>>(
      hs, qkv_w, proj_w, hs_b, qkvw_b, projw_b);

  gemm1_3r<<<dim3(S_TOT / 256, TDIM / 256), 512, 98304, stream>>>(
      hs_b, qkvw_b, qkv_b, qkv_b16);

  pack_all<<<QK_BLOCKS + V_BLOCKS, 256, 0, stream>>>(qkv_b16, cosp, sinp, Qp, Kp, Vp);

  attn_mfma<<<dim3(768), 256, 0, stream>>>(Qp, Kp, Vp, attn_b);

  gemm2_3r<<<dim3(S_TOT / 128, DIM / 128), 512, 98304, stream>>>(
      attn_b, projw_b, proj_b, out_f);
}